// Round 9
// baseline (19641.304 us; speedup 1.0000x reference)
//
#include <hip/hip_runtime.h>
#include <hip/hip_bf16.h>
#include <stdint.h>

// LSTM decoder: H=1024, B=4096, T=128, IN=1.
// R20 = R19's GEMM/epilogue (m97-style 2-barrier loop, BM=128 x BN=256,
// BKK=64, XOR swizzle, gload_lds w16 — measured best structure) made
// PERSISTENT:
//  - one launch, 512 blocks @ __launch_bounds__(256,2) = exact 2-block/CU
//    capacity, all co-resident (documented persistent-kernel pattern).
//  - dependency is only 16 blocks wide: batch-group mb's step t+1 needs
//    h(t) from the 16 jb2-blocks of the SAME mb. Per-mb monotonic arrival
//    counter; release = threadfence+syncthreads+tid0 atomicAdd; acquire =
//    tid0 spin (cnt>=16t) + syncthreads + threadfence (L1 invalidate).
//    Correctness is device-scope-fence based, placement-independent.
//  - block map puts a group's 16 blocks on one XCD heuristically
//    (mb&7 == bid&7): h handoff + pred atomics L2-local.
//  - c pinned in registers across all 128 steps as packed bf16 pairs
//    (16 VGPRs): same rounding path as the old cbuf roundtrip (absmax
//    unchanged), -16 MB/step traffic. cbuf/prep_c deleted.
//  - B tile-0 prestaged BEFORE the spin (Wr read-only; prior step's LDS
//    reads drained by the release barrier) to hide spin dead-time.
// R13-R18 schedule rewrites (51-59us) all lost to this structure; reverted.

#define HH 1024
#define BB 4096
#define TT 128

#define BM 128   // batch rows per block
#define BKK 64   // K tile

typedef __bf16 bf16;
typedef __bf16 v8bf __attribute__((ext_vector_type(8)));
typedef float f32x4 __attribute__((ext_vector_type(4)));

__device__ __forceinline__ float fast_sigmoid(float x) {
    return 1.0f / (1.0f + __expf(-x));
}
__device__ __forceinline__ float fast_tanh(float x) {
    return 1.0f - 2.0f / (__expf(2.0f * x) + 1.0f);
}

__device__ __forceinline__ void gload_lds16(const void* g, void* l) {
    __builtin_amdgcn_global_load_lds(
        (const __attribute__((address_space(1))) uint32_t*)(uintptr_t)g,
        (__attribute__((address_space(3))) uint32_t*)(uint32_t)(uintptr_t)l,
        16, 0, 0);
}

__device__ __forceinline__ unsigned short bf16_bits(float x) {
    bf16 h = (bf16)x;
    unsigned short u;
    __builtin_memcpy(&u, &h, 2);
    return u;
}
__device__ __forceinline__ float bits_to_f32(unsigned int us16) {
    union { unsigned int u; float f; } v;
    v.u = us16 << 16;
    return v.f;
}

// ---- Prologue kernels ------------------------------------------------------

// Wr row layout: jb2*256 + g*64 + jj  <->  Whh row g*HH + jb2*64 + jj
// Wr0 = pure Whh (for t=0); Wr1 = Whh + Wih (x) Wout (for t>=1).
__global__ void prep_weights(const float* __restrict__ Whh,
                             const float* __restrict__ bih,
                             const float* __restrict__ bhh,
                             const float* __restrict__ Wih,
                             const float* __restrict__ Wout,
                             const float* __restrict__ bout,
                             bf16* __restrict__ Wr0, bf16* __restrict__ Wr1,
                             float* __restrict__ bias0, float* __restrict__ bias1) {
    int idx = blockIdx.x * blockDim.x + threadIdx.x;
    if (idx < 4 * HH * HH) {
        int k   = idx & (HH - 1);
        int row = idx >> 10;
        int jb2 = row >> 8;
        int g   = (row >> 6) & 3;
        int jj  = row & 63;
        int srow = g * HH + jb2 * 64 + jj;
        float wv = Whh[srow * HH + k];
        Wr0[idx] = (bf16)wv;
        Wr1[idx] = (bf16)(wv + Wih[srow] * Wout[k]);
    }
    if (idx < 4 * HH) {
        float b = bih[idx] + bhh[idx];
        bias0[idx] = b;
        bias1[idx] = b + Wih[idx] * bout[0];
    }
}

__global__ void prep_h(const float* __restrict__ h0, bf16* __restrict__ hb) {
    int idx = blockIdx.x * blockDim.x + threadIdx.x;
    if (idx < BB * HH) hb[idx] = (bf16)h0[idx];
}

// all pred slots = b_out; atomics add the raw dot on top; zero sync counters
__global__ void prep_pred(float* __restrict__ predbuf, const float* __restrict__ b_out,
                          unsigned int* __restrict__ cnt) {
    int idx = blockIdx.x * blockDim.x + threadIdx.x;
    if (idx < (TT + 1) * BB) predbuf[idx] = b_out[0];
    if (idx < 32) cnt[idx] = 0;
}

// ---- Persistent fused LSTM -------------------------------------------------
// 512 blocks: bid -> xcd=bid&7, s=bid>>3; jb2=s>>2 (0..15), mb=(s&3)*8+xcd
// (0..31). Group(mb) = 16 blocks (all jb2), same XCD heuristically.
// Block tile per step: 128 batch x 256 weight rows (m97 2-barrier loop).

__global__ __launch_bounds__(256, 2)
void lstm_persist(const float* __restrict__ c0,
                  bf16* __restrict__ hb0, bf16* __restrict__ hb1,
                  const bf16* __restrict__ Wr0, const bf16* __restrict__ Wr1,
                  const float* __restrict__ bias0, const float* __restrict__ bias1,
                  const float* __restrict__ Wout,
                  float* __restrict__ predbuf,
                  unsigned int* __restrict__ cnt) {
    // unpadded 128-B rows, XOR-swizzled: phys 16B-chunk = logical ^ (row&7)
    __shared__ bf16 As[BM][BKK];        // h tile: 128 x 64      (16 KB)
    __shared__ bf16 Bs[2 * BM][BKK];    // weights: 256 x 64     (32 KB)

    const int tid   = threadIdx.x;
    const int lane  = tid & 63;
    const int w     = tid >> 6;
    const int waveM = w >> 1, waveN = w & 1;
    const int quad  = lane >> 4, l15 = lane & 15;

    const int bid = blockIdx.x;
    const int xcd = bid & 7, s = bid >> 3;     // s 0..63
    const int jb2 = s >> 2;                    // 0..15 weight group
    const int mb  = (s & 3) * 8 + xcd;         // 0..31 batch group
    const int blockB = mb * BM;

    const int r8  = lane >> 3;        // 0..7
    const int gc  = (lane & 7) ^ r8;  // swizzled global 16B-chunk for staging
    const int swr = l15 & 7;          // read-side swizzle key (row & 7)

    // constants across steps
    float wov[2];
    int jj[2];
#pragma unroll
    for (int jh = 0; jh < 2; jh++) {
        jj[jh] = jb2 * 64 + waveN * 32 + jh * 16 + l15;
        wov[jh] = Wout[jj[jh]];
    }

    // c pinned in registers: creg[mi*4+r] = packed {jh0 lo16, jh1 hi16}
    unsigned int creg[16];
#pragma unroll
    for (int mi = 0; mi < 4; mi++)
#pragma unroll
        for (int r = 0; r < 4; r++) {
            const int b = blockB + waveM * 64 + mi * 16 + quad * 4 + r;
            const unsigned int u0 = bf16_bits(c0[(size_t)b * HH + jj[0]]);
            const unsigned int u1 = bf16_bits(c0[(size_t)b * HH + jj[1]]);
            creg[mi * 4 + r] = u0 | (u1 << 16);
        }

    for (int t = 0; t < TT; t++) {
        const bf16* hread  = (t & 1) ? hb1 : hb0;
        bf16*       hwrite = (t & 1) ? hb0 : hb1;
        const bf16* Bsrc   = ((t == 0) ? Wr0 : Wr1) + (size_t)jb2 * 256 * HH;
        const float* biasp = (t == 0) ? bias0 : bias1;
        const bf16* Asrc   = hread + (size_t)blockB * HH;
        float* predw = predbuf + (size_t)(t + 1) * BB;

        // prestage B tile 0 during the spin (Wr read-only; previous step's
        // Bs reads drained by the release barrier below)
#pragma unroll
        for (int c2 = 0; c2 < 8; c2++) {
            const int rowb = w * 64 + c2 * 8;
            gload_lds16(Bsrc + (size_t)(rowb + r8) * HH + gc * 8, &Bs[rowb][0]);
        }
        // acquire: wait for group step t-1 arrivals
        if (t > 0) {
            if (tid == 0) {
                while (atomicAdd(&cnt[mb], 0u) < 16u * (unsigned)t)
                    __builtin_amdgcn_s_sleep(2);
            }
        }
        __syncthreads();
        __threadfence();   // invalidate L1 before reading sibling h writes

        // bias-initialized accumulators
        float bsvv[2][4];
#pragma unroll
        for (int jh = 0; jh < 2; jh++)
#pragma unroll
            for (int g = 0; g < 4; g++) bsvv[jh][g] = biasp[g * HH + jj[jh]];
        f32x4 acc[4][8];
#pragma unroll
        for (int mi = 0; mi < 4; mi++)
#pragma unroll
            for (int g = 0; g < 4; g++)
#pragma unroll
                for (int jh = 0; jh < 2; jh++) {
                    const float bv = bsvv[jh][g];
                    acc[mi][g * 2 + jh] = (f32x4){bv, bv, bv, bv};
                }

        for (int k0 = 0; k0 < HH; k0 += BKK) {
            // A: wave stages rows [w*32, w*32+32) — 4 calls
#pragma unroll
            for (int c2 = 0; c2 < 4; c2++) {
                const int rowb = w * 32 + c2 * 8;
                gload_lds16(Asrc + (size_t)(rowb + r8) * HH + k0 + gc * 8,
                            &As[rowb][0]);
            }
            // B: tile 0 was prestaged; later tiles staged here
            if (k0) {
#pragma unroll
                for (int c2 = 0; c2 < 8; c2++) {
                    const int rowb = w * 64 + c2 * 8;
                    gload_lds16(Bsrc + (size_t)(rowb + r8) * HH + k0 + gc * 8,
                                &Bs[rowb][0]);
                }
            }
            asm volatile("s_waitcnt vmcnt(0)" ::: "memory");
            __syncthreads();
#pragma unroll
            for (int kk = 0; kk < 2; kk++) {
                v8bf a[4], b[8];
                const int pch = ((kk * 4 + quad) ^ swr) * 8;
#pragma unroll
                for (int mi = 0; mi < 4; mi++)
                    a[mi] = *(const v8bf*)&As[waveM * 64 + mi * 16 + l15][pch];
#pragma unroll
                for (int g = 0; g < 4; g++)
#pragma unroll
                    for (int jh = 0; jh < 2; jh++)
                        b[g * 2 + jh] = *(const v8bf*)
                            &Bs[g * 64 + waveN * 32 + jh * 16 + l15][pch];
#pragma unroll
                for (int mi = 0; mi < 4; mi++)
#pragma unroll
                    for (int nt = 0; nt < 8; nt++)
                        acc[mi][nt] = __builtin_amdgcn_mfma_f32_16x16x32_bf16(
                            a[mi], b[nt], acc[mi][nt], 0, 0, 0);
            }
            __syncthreads();
        }

        // Epilogue: acc[mi][g*2+jh][r] = gate g (bias incl.) at (batch, j)
#pragma unroll
        for (int mi = 0; mi < 4; mi++) {
#pragma unroll
            for (int r = 0; r < 4; r++) {
                const int b = blockB + waveM * 64 + mi * 16 + quad * 4 + r;
                const unsigned int cpk = creg[mi * 4 + r];
                unsigned int cnew = 0;
                float pacc = 0.0f;
#pragma unroll
                for (int jh = 0; jh < 2; jh++) {
                    const float gi = acc[mi][0 + jh][r];
                    const float gf = acc[mi][2 + jh][r];
                    const float gg = acc[mi][4 + jh][r];
                    const float go = acc[mi][6 + jh][r];
                    const float cprev =
                        bits_to_f32(jh ? (cpk >> 16) : (cpk & 0xffffu));
                    const float cn = fast_sigmoid(gf) * cprev
                                   + fast_sigmoid(gi) * fast_tanh(gg);
                    const unsigned int cb = bf16_bits(cn);  // same rounding as cbuf
                    cnew |= jh ? (cb << 16) : cb;
                    const float hn =
                        fast_sigmoid(go) * bits_to_f32(cb) == 0.0f
                            ? fast_sigmoid(go) * fast_tanh(bits_to_f32(cb))
                            : fast_sigmoid(go) * fast_tanh(cn);
                    hwrite[(size_t)b * HH + jj[jh]] = (bf16)hn;
                    pacc += hn * wov[jh];
                }
                creg[mi * 4 + r] = cnew;
                pacc += __shfl_xor(pacc, 1);
                pacc += __shfl_xor(pacc, 2);
                pacc += __shfl_xor(pacc, 4);
                pacc += __shfl_xor(pacc, 8);
                if (l15 == 0) atomicAdd(&predw[b], pacc);
            }
        }

        // release: arrivals for step t
        __threadfence();
        __syncthreads();
        if (tid == 0 && t < TT - 1) atomicAdd(&cnt[mb], 1u);
    }
}

// ---- Output transpose: out[b][t] = pred_t[b] ------------------------------

__global__ void write_out(const float* __restrict__ predbuf, float* __restrict__ out) {
    int idx = blockIdx.x * blockDim.x + threadIdx.x;
    if (idx < BB * TT) {
        int t = idx & (TT - 1);
        int b = idx >> 7;
        out[idx] = predbuf[(size_t)(t + 1) * BB + b];
    }
}

// ---- Host launch -----------------------------------------------------------

extern "C" void kernel_launch(void* const* d_in, const int* in_sizes, int n_in,
                              void* d_out, int out_size, void* d_ws, size_t ws_size,
                              hipStream_t stream) {
    const float* hidden = (const float*)d_in[0];
    const float* cell   = (const float*)d_in[1];
    const float* Wih    = (const float*)d_in[2];
    const float* Whh    = (const float*)d_in[3];
    const float* bih    = (const float*)d_in[4];
    const float* bhh    = (const float*)d_in[5];
    const float* Wout   = (const float*)d_in[6];
    const float* bout   = (const float*)d_in[7];
    float* out = (float*)d_out;

    char* ws = (char*)d_ws;
    bf16* Wr0 = (bf16*)ws;       ws += (size_t)4 * HH * HH * 2;   // 8 MB
    bf16* Wr1 = (bf16*)ws;       ws += (size_t)4 * HH * HH * 2;   // 8 MB
    bf16* hb0 = (bf16*)ws;       ws += (size_t)BB * HH * 2;       // 8 MB
    bf16* hb1 = (bf16*)ws;       ws += (size_t)BB * HH * 2;       // 8 MB
    float* bias0 = (float*)ws;   ws += (size_t)4 * HH * 4;        // 16 KB
    float* bias1 = (float*)ws;   ws += (size_t)4 * HH * 4;        // 16 KB
    float* predbuf = (float*)ws; ws += (size_t)(TT + 1) * BB * 4; // 2.1 MB
    unsigned int* cnt = (unsigned int*)ws; ws += 32 * 4;

    prep_weights<<<(4 * HH * HH + 255) / 256, 256, 0, stream>>>(
        Whh, bih, bhh, Wih, Wout, bout, Wr0, Wr1, bias0, bias1);
    prep_h<<<(BB * HH + 255) / 256, 256, 0, stream>>>(hidden, hb0);
    prep_pred<<<((TT + 1) * BB + 255) / 256, 256, 0, stream>>>(predbuf, bout, cnt);

    lstm_persist<<<512, 256, 0, stream>>>(
        cell, hb0, hb1, Wr0, Wr1, bias0, bias1, Wout, predbuf, cnt);

    write_out<<<(BB * TT + 255) / 256, 256, 0, stream>>>(predbuf, out);
}

// Round 11
// 6505.157 us; speedup vs baseline: 3.0193x; 3.0193x over previous
//
#include <hip/hip_runtime.h>
#include <hip/hip_bf16.h>
#include <stdint.h>

// LSTM decoder: H=1024, B=4096, T=128, IN=1.
// R22 = R21 (m201-style T3+T4 schedule at 256x256, FIFO-ledger counted
// vmcnt) with the RACE FIX: A-quadrant decomposition now matches the staged
// halves. R21 read As rows waveM*128+QM*64 at p0 -> waveM=1 touched A-hi
// (certified only at p2) with 1 phase of slack -> timing-dependent wrong
// gates (tripwire divergence). Now quadrant QM = rows QM*128 + waveM*64:
// p0 reads rows 0..127 (A-lo, certified by p0's vmcnt(6)), p2 reads rows
// 128..255 (A-hi, certified by p2's vmcnt(6)). Epilogue batch remapped:
// bq = blockB + (mi>>2)*128 + waveM*64 + (mi&3)*16 + quad*4 + r.
// Full ledger re-audit: p0 {Alo,Blo} ok, p1 {Bhi} ok, p2 {Ahi} ok, p3 no
// reads; last tile drains {4,2,0}; LDS WAR separations unchanged.
//  - 512 thr / 8 waves (2M x 4N), BK=64, 2-dbuf 128 KiB LDS, grid 256.
//  - stage order tile t+1: A-lo@p0, B-lo@p1, B-hi@p2, A-hi@p3 (2/phase).
//  - phase = {stage -> vmcnt(6) -> BAR -> ds_read -> setprio+16 MFMA -> BAR}.
//  - epilogue/numerics/prep = R19 verbatim; 2D XCD map (FETCH 28.9 MB).

#define HH 1024
#define BB 4096
#define TT 128

#define BM 256            // batch rows per block
#define BN 256            // weight rows per block = 4 gates x 64 j
#define BKK 64            // K tile
#define NT (HH / BKK)     // 16 K-tiles

typedef __bf16 bf16;
typedef __bf16 v8bf __attribute__((ext_vector_type(8)));
typedef float f32x4 __attribute__((ext_vector_type(4)));

__device__ __forceinline__ float fast_sigmoid(float x) {
    return 1.0f / (1.0f + __expf(-x));
}
__device__ __forceinline__ float fast_tanh(float x) {
    return 1.0f - 2.0f / (__expf(2.0f * x) + 1.0f);
}

__device__ __forceinline__ void gload_lds16(const void* g, void* l) {
    __builtin_amdgcn_global_load_lds(
        (const __attribute__((address_space(1))) uint32_t*)(uintptr_t)g,
        (__attribute__((address_space(3))) uint32_t*)(uint32_t)(uintptr_t)l,
        16, 0, 0);
}

#define FENCE() asm volatile("" ::: "memory")
#define BAR() do { FENCE(); __builtin_amdgcn_s_barrier(); FENCE(); } while (0)
#define WV6() asm volatile("s_waitcnt vmcnt(6)" ::: "memory")
#define WV4() asm volatile("s_waitcnt vmcnt(4)" ::: "memory")
#define WV2() asm volatile("s_waitcnt vmcnt(2)" ::: "memory")
#define WV0() asm volatile("s_waitcnt vmcnt(0)" ::: "memory")

// ---- Prologue kernels ------------------------------------------------------

__global__ void prep_weights(const float* __restrict__ Whh,
                             const float* __restrict__ bih,
                             const float* __restrict__ bhh,
                             const float* __restrict__ Wih,
                             const float* __restrict__ Wout,
                             const float* __restrict__ bout,
                             bf16* __restrict__ Wr0, bf16* __restrict__ Wr1,
                             float* __restrict__ bias0, float* __restrict__ bias1) {
    int idx = blockIdx.x * blockDim.x + threadIdx.x;
    if (idx < 4 * HH * HH) {
        int k   = idx & (HH - 1);
        int row = idx >> 10;
        int nb  = row >> 8;
        int g   = (row >> 6) & 3;
        int jj  = row & 63;
        int srow = g * HH + nb * 64 + jj;
        float wv = Whh[srow * HH + k];
        Wr0[idx] = (bf16)wv;
        Wr1[idx] = (bf16)(wv + Wih[srow] * Wout[k]);
    }
    if (idx < 4 * HH) {
        float b = bih[idx] + bhh[idx];
        bias0[idx] = b;
        bias1[idx] = b + Wih[idx] * bout[0];
    }
}

__global__ void prep_h(const float* __restrict__ h0, bf16* __restrict__ hb) {
    int idx = blockIdx.x * blockDim.x + threadIdx.x;
    if (idx < BB * HH) hb[idx] = (bf16)h0[idx];
}

__global__ void prep_c(const float* __restrict__ c0, bf16* __restrict__ cb) {
    int idx = blockIdx.x * blockDim.x + threadIdx.x;
    if (idx < BB * HH) cb[idx] = (bf16)c0[idx];
}

__global__ void prep_pred(float* __restrict__ predbuf, const float* __restrict__ b_out) {
    int idx = blockIdx.x * blockDim.x + threadIdx.x;
    if (idx < (TT + 1) * BB) predbuf[idx] = b_out[0];
}

// ---- Per-step fused GEMM + cell update ------------------------------------
// grid 256 = 16 nb x 16 mb (2D XCD map). Block 256 batch x 256 wrows.
// Wave (waveM 0..1, waveN 0..3); acc[QM*4+mi][g] -> batch row
// QM*128 + waveM*64 + mi*16 + quad*4 + r.

#define STG_A(HF, TGT, KN)                                                     \
    _Pragma("unroll")                                                          \
    for (int c = 0; c < 2; c++) {                                              \
        const int rowb = (HF) * 128 + w * 16 + c * 8;                          \
        gload_lds16(Asrc + (size_t)(rowb + r8) * HH + (KN) + gc8,              \
                    &As[TGT][rowb][0]);                                        \
    }
#define STG_B(HF, TGT, KN)                                                     \
    _Pragma("unroll")                                                          \
    for (int c = 0; c < 2; c++) {                                              \
        const int rowb = (HF) * 128 + w * 16 + c * 8;                          \
        gload_lds16(Bsrc + (size_t)(rowb + r8) * HH + (KN) + gc8,              \
                    &Bs[TGT][rowb][0]);                                        \
    }

// quadrant QM = rows QM*128 + waveM*64 (+mi*16+l15): stays within half QM.
#define READ_A(BUF, QM)                                                        \
    _Pragma("unroll")                                                          \
    for (int mi = 0; mi < 4; mi++)                                             \
        _Pragma("unroll")                                                      \
        for (int kk = 0; kk < 2; kk++)                                         \
            a[mi][kk] = *(const v8bf*)                                         \
                &As[BUF][(QM) * 128 + waveM * 64 + mi * 16 + l15]              \
                    [((kk * 4 + quad) ^ swr) * 8];

#define READ_B(BUF, G0)                                                        \
    _Pragma("unroll")                                                          \
    for (int g2 = 0; g2 < 2; g2++)                                             \
        _Pragma("unroll")                                                      \
        for (int kk = 0; kk < 2; kk++)                                         \
            b[(G0) + g2][kk] = *(const v8bf*)                                  \
                &Bs[BUF][((G0) + g2) * 64 + waveN * 16 + l15]                  \
                    [((kk * 4 + quad) ^ swr) * 8];

#define MFMA_Q(QM, QN)                                                         \
    __builtin_amdgcn_s_setprio(1);                                             \
    _Pragma("unroll")                                                          \
    for (int mi = 0; mi < 4; mi++)                                             \
        _Pragma("unroll")                                                      \
        for (int g2 = 0; g2 < 2; g2++)                                         \
            _Pragma("unroll")                                                  \
            for (int kk = 0; kk < 2; kk++)                                     \
                acc[(QM) * 4 + mi][(QN) * 2 + g2] =                            \
                    __builtin_amdgcn_mfma_f32_16x16x32_bf16(                   \
                        a[mi][kk], b[(QN) * 2 + g2][kk],                       \
                        acc[(QM) * 4 + mi][(QN) * 2 + g2], 0, 0, 0);           \
    __builtin_amdgcn_s_setprio(0);

// DOST: 1 = stage tile T+1 into buf^1. W0/W1/W2 = wait macros for p0/p1/p2.
#define TILE_BODY(BUF, T, DOST, W0, W1, W2)                                    \
    {                                                                          \
        v8bf a[4][2], b[4][2];                                                 \
        const int kn_ = ((T) + 1) * BKK;                                       \
        /* p0: stage A-lo(t+1); certify Alo+Blo(t); reads A rows 0..127 */     \
        if (DOST) { STG_A(0, 1 - (BUF), kn_) }                                 \
        W0();                                                                  \
        BAR();                                                                 \
        READ_A(BUF, 0)                                                         \
        READ_B(BUF, 0)                                                         \
        MFMA_Q(0, 0)                                                           \
        BAR();                                                                 \
        /* p1: stage B-lo(t+1); certify Bhi(t); reads B rows 128..255 */       \
        if (DOST) { STG_B(0, 1 - (BUF), kn_) }                                 \
        W1();                                                                  \
        BAR();                                                                 \
        READ_B(BUF, 2)                                                         \
        MFMA_Q(0, 1)                                                           \
        BAR();                                                                 \
        /* p2: stage B-hi(t+1); certify Ahi(t); reads A rows 128..255 */       \
        if (DOST) { STG_B(1, 1 - (BUF), kn_) }                                 \
        W2();                                                                  \
        BAR();                                                                 \
        READ_A(BUF, 1)                                                         \
        MFMA_Q(1, 0)                                                           \
        BAR();                                                                 \
        /* p3: stage A-hi(t+1); no wait, no reads */                           \
        if (DOST) { STG_A(1, 1 - (BUF), kn_) }                                 \
        MFMA_Q(1, 1)                                                           \
        BAR();                                                                 \
    }

__global__ __launch_bounds__(512, 2)
void lstm_step(const bf16* __restrict__ hread, bf16* __restrict__ hwrite,
               bf16* __restrict__ cbuf,
               const bf16* __restrict__ Wr, const float* __restrict__ biasp,
               const float* __restrict__ Wout, float* __restrict__ predbuf_w) {
    // unpadded 128-B rows, XOR-swizzled: phys 16B-chunk = logical ^ (row&7)
    __shared__ __align__(16) bf16 As[2][BM][BKK];   // 64 KB
    __shared__ __align__(16) bf16 Bs[2][BN][BKK];   // 64 KB

    const int tid   = threadIdx.x;
    const int lane  = tid & 63;
    const int w     = tid >> 6;        // 0..7
    const int waveM = w >> 2;          // 0..1
    const int waveN = w & 3;           // 0..3
    const int quad  = lane >> 4, l15 = lane & 15;
    const int swr   = l15 & 7;

    // 2D bijective XCD map: xcd owns nb 4-group and mb 8-group
    const int bid = blockIdx.x;
    const int xcd = bid & 7, loc = bid >> 3;        // loc 0..31
    const int nb  = (xcd & 3) * 4 + (loc & 3);      // 0..15
    const int mb  = (xcd >> 2) * 8 + (loc >> 2);    // 0..15
    const int blockB = mb * BM;

    const bf16* Asrc = hread + (size_t)blockB * HH;
    const bf16* Bsrc = Wr + (size_t)nb * BN * HH;

    const int r8  = lane >> 3;
    const int gc8 = ((lane & 7) ^ r8) * 8;

    const int j = nb * 64 + waveN * 16 + l15;
    const float wo = Wout[j];

    f32x4 acc[8][4];
#pragma unroll
    for (int g = 0; g < 4; g++) {
        const float bv = biasp[g * HH + j];
#pragma unroll
        for (int mi = 0; mi < 8; mi++)
            acc[mi][g] = (f32x4){bv, bv, bv, bv};
    }

    // ---- prologue: stage tile 0 (order Alo,Blo,Bhi,Ahi -> FIFO ledger) ----
    STG_A(0, 0, 0)
    STG_B(0, 0, 0)
    STG_B(1, 0, 0)
    STG_A(1, 0, 0)
    // main loop waits handle certification (t=0 p0: after-Blo = 6 ✓)

    // ---- 16 K-tiles: t=0..14 uniform, 15 drains {4,2,0} ----
#pragma unroll 1
    for (int tt = 0; tt < 7; tt++) {
        TILE_BODY(0, 2 * tt,     1, WV6, WV6, WV6)
        TILE_BODY(1, 2 * tt + 1, 1, WV6, WV6, WV6)
    }
    TILE_BODY(0, 14, 1, WV6, WV6, WV6)
    TILE_BODY(1, 15, 0, WV4, WV2, WV0)

    // ---- Epilogue: acc[mi][g][r] at batch
    //   bq = blockB + (mi>>2)*128 + waveM*64 + (mi&3)*16 + quad*4 + r
#pragma unroll
    for (int mi = 0; mi < 8; mi++) {
#pragma unroll
        for (int r = 0; r < 4; r++) {
            const int bq = blockB + (mi >> 2) * 128 + waveM * 64
                         + (mi & 3) * 16 + quad * 4 + r;
            const float gi = acc[mi][0][r];
            const float gf = acc[mi][1][r];
            const float gg = acc[mi][2][r];
            const float go = acc[mi][3][r];
            const float cprev = (float)cbuf[(size_t)bq * HH + j];
            const float cn = fast_sigmoid(gf) * cprev
                           + fast_sigmoid(gi) * fast_tanh(gg);
            cbuf[(size_t)bq * HH + j] = (bf16)cn;
            const float hn = fast_sigmoid(go) * fast_tanh(cn);
            hwrite[(size_t)bq * HH + j] = (bf16)hn;
            float pacc = hn * wo;
            pacc += __shfl_xor(pacc, 1);
            pacc += __shfl_xor(pacc, 2);
            pacc += __shfl_xor(pacc, 4);
            pacc += __shfl_xor(pacc, 8);
            if (l15 == 0) atomicAdd(&predbuf_w[bq], pacc);
        }
    }
}

// ---- Output transpose: out[b][t] = pred_t[b] ------------------------------

__global__ void write_out(const float* __restrict__ predbuf, float* __restrict__ out) {
    int idx = blockIdx.x * blockDim.x + threadIdx.x;
    if (idx < BB * TT) {
        int t = idx & (TT - 1);
        int b = idx >> 7;
        out[idx] = predbuf[(size_t)(t + 1) * BB + b];
    }
}

// ---- Host launch -----------------------------------------------------------

extern "C" void kernel_launch(void* const* d_in, const int* in_sizes, int n_in,
                              void* d_out, int out_size, void* d_ws, size_t ws_size,
                              hipStream_t stream) {
    const float* hidden = (const float*)d_in[0];
    const float* cell   = (const float*)d_in[1];
    const float* Wih    = (const float*)d_in[2];
    const float* Whh    = (const float*)d_in[3];
    const float* bih    = (const float*)d_in[4];
    const float* bhh    = (const float*)d_in[5];
    const float* Wout   = (const float*)d_in[6];
    const float* bout   = (const float*)d_in[7];
    float* out = (float*)d_out;

    char* ws = (char*)d_ws;
    bf16* Wr0 = (bf16*)ws;       ws += (size_t)4 * HH * HH * 2;   // 8 MB
    bf16* Wr1 = (bf16*)ws;       ws += (size_t)4 * HH * HH * 2;   // 8 MB
    bf16* hb0 = (bf16*)ws;       ws += (size_t)BB * HH * 2;       // 8 MB
    bf16* hb1 = (bf16*)ws;       ws += (size_t)BB * HH * 2;       // 8 MB
    bf16* cbuf = (bf16*)ws;      ws += (size_t)BB * HH * 2;       // 8 MB
    float* bias0 = (float*)ws;   ws += (size_t)4 * HH * 4;        // 16 KB
    float* bias1 = (float*)ws;   ws += (size_t)4 * HH * 4;        // 16 KB
    float* predbuf = (float*)ws; ws += (size_t)(TT + 1) * BB * 4; // 2.1 MB

    prep_weights<<<(4 * HH * HH + 255) / 256, 256, 0, stream>>>(
        Whh, bih, bhh, Wih, Wout, bout, Wr0, Wr1, bias0, bias1);
    prep_h<<<(BB * HH + 255) / 256, 256, 0, stream>>>(hidden, hb0);
    prep_c<<<(BB * HH + 255) / 256, 256, 0, stream>>>(cell, cbuf);
    prep_pred<<<((TT + 1) * BB + 255) / 256, 256, 0, stream>>>(predbuf, bout);

    bf16* hb[2] = {hb0, hb1};
    for (int t = 0; t < TT; t++) {
        const bf16* hr = hb[t & 1];
        bf16* hw = hb[(t + 1) & 1];
        const bf16* Wr   = (t == 0) ? Wr0 : Wr1;
        const float* bsp = (t == 0) ? bias0 : bias1;
        lstm_step<<<256, 512, 0, stream>>>(
            hr, hw, cbuf, Wr, bsp, Wout, predbuf + (size_t)(t + 1) * BB);
    }

    write_out<<<(BB * TT + 255) / 256, 256, 0, stream>>>(predbuf, out);
}

// Round 12
// 6156.645 us; speedup vs baseline: 3.1903x; 1.0566x over previous
//
#include <hip/hip_runtime.h>
#include <hip/hip_bf16.h>
#include <stdint.h>

// LSTM decoder: H=1024, B=4096, T=128, IN=1.
// R23 = R19 (champion, 5164us total: m97 2-barrier loop, BM=128 x BN=256,
// BKK=64, XOR swizzle, gload_lds w16, 2 blocks/CU, 2D bijective XCD map)
// + ONE change: cprev prefetched into registers BEFORE the K-loop.
//  - epilogue previously issued 32 scattered 2B cbuf loads per lane in the
//    serial tail after the GEMM (L2-latency chain). Block exclusively owns
//    its (b,j) c-elements (same block wrote them at step t-1, same XCD ->
//    L2 hit) -> early read is race-free; numerics identical.
//  - c loads share the vmcnt FIFO and retire before tile-0's drain; no
//    per-tile wait cost. VGPR ~108 -> ~140 (fine at 2 waves/SIMD).
// Falsified this session (all lost to this structure): 4-phase vmcnt(2)
// R13, burst+drain R14/R16, BK=32 triple-buffer vmcnt(6) R18, persistent
// spin R20, 8-phase FIFO-ledger counted vmcnt R21/R22 (53us vs 49us here).

#define HH 1024
#define BB 4096
#define TT 128

#define BM 128   // batch rows per block
#define BKK 64   // K tile

typedef __bf16 bf16;
typedef __bf16 v8bf __attribute__((ext_vector_type(8)));
typedef float f32x4 __attribute__((ext_vector_type(4)));

__device__ __forceinline__ float fast_sigmoid(float x) {
    return 1.0f / (1.0f + __expf(-x));
}
__device__ __forceinline__ float fast_tanh(float x) {
    return 1.0f - 2.0f / (__expf(2.0f * x) + 1.0f);
}

__device__ __forceinline__ void gload_lds16(const void* g, void* l) {
    __builtin_amdgcn_global_load_lds(
        (const __attribute__((address_space(1))) uint32_t*)(uintptr_t)g,
        (__attribute__((address_space(3))) uint32_t*)(uint32_t)(uintptr_t)l,
        16, 0, 0);
}

// ---- Prologue kernels ------------------------------------------------------

// Wr row layout: jb2*256 + g*64 + jj  <->  Whh row g*HH + jb2*64 + jj
// Wr0 = pure Whh (for t=0); Wr1 = Whh + Wih (x) Wout (for t>=1).
__global__ void prep_weights(const float* __restrict__ Whh,
                             const float* __restrict__ bih,
                             const float* __restrict__ bhh,
                             const float* __restrict__ Wih,
                             const float* __restrict__ Wout,
                             const float* __restrict__ bout,
                             bf16* __restrict__ Wr0, bf16* __restrict__ Wr1,
                             float* __restrict__ bias0, float* __restrict__ bias1) {
    int idx = blockIdx.x * blockDim.x + threadIdx.x;
    if (idx < 4 * HH * HH) {
        int k   = idx & (HH - 1);
        int row = idx >> 10;
        int jb2 = row >> 8;
        int g   = (row >> 6) & 3;
        int jj  = row & 63;
        int srow = g * HH + jb2 * 64 + jj;
        float wv = Whh[srow * HH + k];
        Wr0[idx] = (bf16)wv;
        Wr1[idx] = (bf16)(wv + Wih[srow] * Wout[k]);
    }
    if (idx < 4 * HH) {
        float b = bih[idx] + bhh[idx];
        bias0[idx] = b;
        bias1[idx] = b + Wih[idx] * bout[0];
    }
}

__global__ void prep_h(const float* __restrict__ h0, bf16* __restrict__ hb) {
    int idx = blockIdx.x * blockDim.x + threadIdx.x;
    if (idx < BB * HH) hb[idx] = (bf16)h0[idx];
}

__global__ void prep_c(const float* __restrict__ c0, bf16* __restrict__ cb) {
    int idx = blockIdx.x * blockDim.x + threadIdx.x;
    if (idx < BB * HH) cb[idx] = (bf16)c0[idx];
}

// all pred slots = b_out; atomics add the raw dot on top
__global__ void prep_pred(float* __restrict__ predbuf, const float* __restrict__ b_out) {
    int idx = blockIdx.x * blockDim.x + threadIdx.x;
    if (idx < (TT + 1) * BB) predbuf[idx] = b_out[0];
}

// ---- Per-step fused GEMM + cell update ------------------------------------
// 512 blocks = 16 jb2 x 32 mb, 2D-XCD-mapped. Block tile: 128 batch x 256
// weight rows. Wave (waveM, waveN): 64 batch x 128 wrows; acc[mi][g*2+jh].

__global__ __launch_bounds__(256, 2)
void lstm_step(const bf16* __restrict__ hread, bf16* __restrict__ hwrite,
               bf16* __restrict__ cbuf,
               const bf16* __restrict__ Wr, const float* __restrict__ biasp,
               const float* __restrict__ Wout, float* __restrict__ predbuf_w) {
    // unpadded 128-B rows, XOR-swizzled: phys 16B-chunk = logical ^ (row&7)
    __shared__ bf16 As[BM][BKK];        // h tile: 128 x 64      (16 KB)
    __shared__ bf16 Bs[2 * BM][BKK];    // weights: 256 x 64     (32 KB)

    const int tid   = threadIdx.x;
    const int lane  = tid & 63;
    const int w     = tid >> 6;
    const int waveM = w >> 1, waveN = w & 1;
    const int quad  = lane >> 4, l15 = lane & 15;

    // 2D bijective XCD remap: XCD x owns jb2 in [(x&3)*4,+4),
    // mb in [(x>>2)*16,+16).  (xcd&3,loc&3)->jb2, (xcd>>2,loc>>2)->mb.
    const int bid = blockIdx.x;
    const int xcd = bid & 7, loc = bid >> 3;        // loc 0..63
    const int jb2 = (xcd & 3) * 4 + (loc & 3);      // 0..15 weight group
    const int blockB = ((xcd >> 2) * 16 + (loc >> 2)) * BM;  // batch base

    const bf16* Asrc = hread + (size_t)blockB * HH;
    const bf16* Bsrc = Wr + (size_t)jb2 * 256 * HH;

    const int r8  = lane >> 3;        // 0..7
    const int gc  = (lane & 7) ^ r8;  // swizzled global 16B-chunk for staging
    const int swr = l15 & 7;          // read-side swizzle key (row & 7)

    // epilogue constants; bias folded into acc init
    float bsvv[2][4], wov[2];
    int jjv[2];
#pragma unroll
    for (int jh = 0; jh < 2; jh++) {
        jjv[jh] = jb2 * 64 + waveN * 32 + jh * 16 + l15;
#pragma unroll
        for (int g = 0; g < 4; g++) bsvv[jh][g] = biasp[g * HH + jjv[jh]];
        wov[jh] = Wout[jjv[jh]];
    }

    f32x4 acc[4][8]; // [m-tile][gate*2 + j-half], bias-initialized
#pragma unroll
    for (int mi = 0; mi < 4; mi++)
#pragma unroll
        for (int g = 0; g < 4; g++)
#pragma unroll
            for (int jh = 0; jh < 2; jh++) {
                const float bv = bsvv[jh][g];
                acc[mi][g * 2 + jh] = (f32x4){bv, bv, bv, bv};
            }

    // c-prefetch: block exclusively owns its (b,j) c-elements (written by
    // this same block last step) -> safe to read before the GEMM. Hides the
    // scattered-load latency under the K-loop instead of the serial tail.
    float cpre[4][4][2];
#pragma unroll
    for (int mi = 0; mi < 4; mi++)
#pragma unroll
        for (int r = 0; r < 4; r++) {
            const int b = blockB + waveM * 64 + mi * 16 + quad * 4 + r;
#pragma unroll
            for (int jh = 0; jh < 2; jh++)
                cpre[mi][r][jh] = (float)cbuf[(size_t)b * HH + jjv[jh]];
        }

    for (int k0 = 0; k0 < HH; k0 += BKK) {
        // A: wave stages rows [w*32, w*32+32) — 4 calls (8 rows x 128 B each)
#pragma unroll
        for (int c2 = 0; c2 < 4; c2++) {
            const int rowb = w * 32 + c2 * 8;
            gload_lds16(Asrc + (size_t)(rowb + r8) * HH + k0 + gc * 8, &As[rowb][0]);
        }
        // B: wave stages rows [w*64, w*64+64) — 8 calls
#pragma unroll
        for (int c2 = 0; c2 < 8; c2++) {
            const int rowb = w * 64 + c2 * 8;
            gload_lds16(Bsrc + (size_t)(rowb + r8) * HH + k0 + gc * 8, &Bs[rowb][0]);
        }
        asm volatile("s_waitcnt vmcnt(0)" ::: "memory");
        __syncthreads();
#pragma unroll
        for (int kk = 0; kk < 2; kk++) {
            v8bf a[4], b[8];
            const int pch = ((kk * 4 + quad) ^ swr) * 8;
#pragma unroll
            for (int mi = 0; mi < 4; mi++)
                a[mi] = *(const v8bf*)&As[waveM * 64 + mi * 16 + l15][pch];
#pragma unroll
            for (int g = 0; g < 4; g++)
#pragma unroll
                for (int jh = 0; jh < 2; jh++)
                    b[g * 2 + jh] =
                        *(const v8bf*)&Bs[g * 64 + waveN * 32 + jh * 16 + l15][pch];
#pragma unroll
            for (int mi = 0; mi < 4; mi++)
#pragma unroll
                for (int nt = 0; nt < 8; nt++)
                    acc[mi][nt] = __builtin_amdgcn_mfma_f32_16x16x32_bf16(
                        a[mi], b[nt], acc[mi][nt], 0, 0, 0);
        }
        __syncthreads();
    }

    // Epilogue: acc[mi][g*2+jh][r] = gate g (bias incl.) at (batch, j):
    //   batch = blockB + waveM*64 + mi*16 + quad*4 + r
    //   j     = jb2*64 + waveN*32 + jh*16 + l15
#pragma unroll
    for (int mi = 0; mi < 4; mi++) {
#pragma unroll
        for (int r = 0; r < 4; r++) {
            const int b = blockB + waveM * 64 + mi * 16 + quad * 4 + r;
            float pacc = 0.0f;
#pragma unroll
            for (int jh = 0; jh < 2; jh++) {
                const int j = jjv[jh];
                const float gi = acc[mi][0 + jh][r];
                const float gf = acc[mi][2 + jh][r];
                const float gg = acc[mi][4 + jh][r];
                const float go = acc[mi][6 + jh][r];
                const float cprev = cpre[mi][r][jh];
                const float cn = fast_sigmoid(gf) * cprev
                               + fast_sigmoid(gi) * fast_tanh(gg);
                cbuf[(size_t)b * HH + j] = (bf16)cn;   // in-place, 1 owner/elem
                const float hn = fast_sigmoid(go) * fast_tanh(cn);
                hwrite[(size_t)b * HH + j] = (bf16)hn;
                pacc += hn * wov[jh];
            }
            pacc += __shfl_xor(pacc, 1);
            pacc += __shfl_xor(pacc, 2);
            pacc += __shfl_xor(pacc, 4);
            pacc += __shfl_xor(pacc, 8);
            if (l15 == 0) atomicAdd(&predbuf_w[b], pacc);
        }
    }
}

// ---- Output transpose: out[b][t] = pred_t[b] ------------------------------

__global__ void write_out(const float* __restrict__ predbuf, float* __restrict__ out) {
    int idx = blockIdx.x * blockDim.x + threadIdx.x;
    if (idx < BB * TT) {
        int t = idx & (TT - 1);
        int b = idx >> 7;
        out[idx] = predbuf[(size_t)(t + 1) * BB + b];
    }
}

// ---- Host launch -----------------------------------------------------------

extern "C" void kernel_launch(void* const* d_in, const int* in_sizes, int n_in,
                              void* d_out, int out_size, void* d_ws, size_t ws_size,
                              hipStream_t stream) {
    const float* hidden = (const float*)d_in[0];
    const float* cell   = (const float*)d_in[1];
    const float* Wih    = (const float*)d_in[2];
    const float* Whh    = (const float*)d_in[3];
    const float* bih    = (const float*)d_in[4];
    const float* bhh    = (const float*)d_in[5];
    const float* Wout   = (const float*)d_in[6];
    const float* bout   = (const float*)d_in[7];
    float* out = (float*)d_out;

    char* ws = (char*)d_ws;
    bf16* Wr0 = (bf16*)ws;       ws += (size_t)4 * HH * HH * 2;   // 8 MB
    bf16* Wr1 = (bf16*)ws;       ws += (size_t)4 * HH * HH * 2;   // 8 MB
    bf16* hb0 = (bf16*)ws;       ws += (size_t)BB * HH * 2;       // 8 MB
    bf16* hb1 = (bf16*)ws;       ws += (size_t)BB * HH * 2;       // 8 MB
    bf16* cbuf = (bf16*)ws;      ws += (size_t)BB * HH * 2;       // 8 MB
    float* bias0 = (float*)ws;   ws += (size_t)4 * HH * 4;        // 16 KB
    float* bias1 = (float*)ws;   ws += (size_t)4 * HH * 4;        // 16 KB
    float* predbuf = (float*)ws; ws += (size_t)(TT + 1) * BB * 4; // 2.1 MB

    prep_weights<<<(4 * HH * HH + 255) / 256, 256, 0, stream>>>(
        Whh, bih, bhh, Wih, Wout, bout, Wr0, Wr1, bias0, bias1);
    prep_h<<<(BB * HH + 255) / 256, 256, 0, stream>>>(hidden, hb0);
    prep_c<<<(BB * HH + 255) / 256, 256, 0, stream>>>(cell, cbuf);
    prep_pred<<<((TT + 1) * BB + 255) / 256, 256, 0, stream>>>(predbuf, bout);

    bf16* hb[2] = {hb0, hb1};
    for (int t = 0; t < TT; t++) {
        const bf16* hr = hb[t & 1];
        bf16* hw = hb[(t + 1) & 1];
        const bf16* Wr   = (t == 0) ? Wr0 : Wr1;
        const float* bsp = (t == 0) ? bias0 : bias1;
        lstm_step<<<512, 256, 0, stream>>>(
            hr, hw, cbuf, Wr, bsp, Wout, predbuf + (size_t)(t + 1) * BB);
    }

    write_out<<<(BB * TT + 255) / 256, 256, 0, stream>>>(predbuf, out);
}

// Round 13
// 5148.170 us; speedup vs baseline: 3.8152x; 1.1959x over previous
//
#include <hip/hip_runtime.h>
#include <hip/hip_bf16.h>
#include <stdint.h>

// LSTM decoder: H=1024, B=4096, T=128, IN=1.
// R24 = R19 verbatim (champion, 5164us total): m97 2-barrier loop,
// BM=128 x BN=256, BKK=64, XOR swizzle, gload_lds w16, 2 blocks/CU,
// 2D bijective XCD map (FETCH 28.9 MB), rank-1 pred fold, bf16 h/c,
// cprev read ADJACENT to cn write in the epilogue (RMW locality).
// Falsified this session (all lost to this structure):
//  R13 4-phase vmcnt(2) 57us | R14/R16 burst+drain 55-59us |
//  R18 BK=32 triple-buffer vmcnt(6) 51us | R20 persistent spin 19.6ms |
//  R21/R22 8-phase FIFO-ledger counted vmcnt 53us |
//  R23 c-prefetch before K-loop: broke cbuf RMW temporal locality ->
//      FETCH 29->40.5 MB, WRITE 18->41.5 MB, +8% time. Reverted.

#define HH 1024
#define BB 4096
#define TT 128

#define BM 128   // batch rows per block
#define BKK 64   // K tile

typedef __bf16 bf16;
typedef __bf16 v8bf __attribute__((ext_vector_type(8)));
typedef float f32x4 __attribute__((ext_vector_type(4)));

__device__ __forceinline__ float fast_sigmoid(float x) {
    return 1.0f / (1.0f + __expf(-x));
}
__device__ __forceinline__ float fast_tanh(float x) {
    return 1.0f - 2.0f / (__expf(2.0f * x) + 1.0f);
}

__device__ __forceinline__ void gload_lds16(const void* g, void* l) {
    __builtin_amdgcn_global_load_lds(
        (const __attribute__((address_space(1))) uint32_t*)(uintptr_t)g,
        (__attribute__((address_space(3))) uint32_t*)(uint32_t)(uintptr_t)l,
        16, 0, 0);
}

// ---- Prologue kernels ------------------------------------------------------

// Wr row layout: jb2*256 + g*64 + jj  <->  Whh row g*HH + jb2*64 + jj
// Wr0 = pure Whh (for t=0); Wr1 = Whh + Wih (x) Wout (for t>=1).
__global__ void prep_weights(const float* __restrict__ Whh,
                             const float* __restrict__ bih,
                             const float* __restrict__ bhh,
                             const float* __restrict__ Wih,
                             const float* __restrict__ Wout,
                             const float* __restrict__ bout,
                             bf16* __restrict__ Wr0, bf16* __restrict__ Wr1,
                             float* __restrict__ bias0, float* __restrict__ bias1) {
    int idx = blockIdx.x * blockDim.x + threadIdx.x;
    if (idx < 4 * HH * HH) {
        int k   = idx & (HH - 1);
        int row = idx >> 10;
        int jb2 = row >> 8;
        int g   = (row >> 6) & 3;
        int jj  = row & 63;
        int srow = g * HH + jb2 * 64 + jj;
        float wv = Whh[srow * HH + k];
        Wr0[idx] = (bf16)wv;
        Wr1[idx] = (bf16)(wv + Wih[srow] * Wout[k]);
    }
    if (idx < 4 * HH) {
        float b = bih[idx] + bhh[idx];
        bias0[idx] = b;
        bias1[idx] = b + Wih[idx] * bout[0];
    }
}

__global__ void prep_h(const float* __restrict__ h0, bf16* __restrict__ hb) {
    int idx = blockIdx.x * blockDim.x + threadIdx.x;
    if (idx < BB * HH) hb[idx] = (bf16)h0[idx];
}

__global__ void prep_c(const float* __restrict__ c0, bf16* __restrict__ cb) {
    int idx = blockIdx.x * blockDim.x + threadIdx.x;
    if (idx < BB * HH) cb[idx] = (bf16)c0[idx];
}

// all pred slots = b_out; atomics add the raw dot on top
__global__ void prep_pred(float* __restrict__ predbuf, const float* __restrict__ b_out) {
    int idx = blockIdx.x * blockDim.x + threadIdx.x;
    if (idx < (TT + 1) * BB) predbuf[idx] = b_out[0];
}

// ---- Per-step fused GEMM + cell update ------------------------------------
// 512 blocks = 16 jb2 x 32 mb, 2D-XCD-mapped. Block tile: 128 batch x 256
// weight rows. Wave (waveM, waveN): 64 batch x 128 wrows; acc[mi][g*2+jh].

__global__ __launch_bounds__(256, 2)
void lstm_step(const bf16* __restrict__ hread, bf16* __restrict__ hwrite,
               bf16* __restrict__ cbuf,
               const bf16* __restrict__ Wr, const float* __restrict__ biasp,
               const float* __restrict__ Wout, float* __restrict__ predbuf_w) {
    // unpadded 128-B rows, XOR-swizzled: phys 16B-chunk = logical ^ (row&7)
    __shared__ bf16 As[BM][BKK];        // h tile: 128 x 64      (16 KB)
    __shared__ bf16 Bs[2 * BM][BKK];    // weights: 256 x 64     (32 KB)

    const int tid   = threadIdx.x;
    const int lane  = tid & 63;
    const int w     = tid >> 6;
    const int waveM = w >> 1, waveN = w & 1;
    const int quad  = lane >> 4, l15 = lane & 15;

    // 2D bijective XCD remap: XCD x owns jb2 in [(x&3)*4,+4),
    // mb in [(x>>2)*16,+16).  (xcd&3,loc&3)->jb2, (xcd>>2,loc>>2)->mb.
    const int bid = blockIdx.x;
    const int xcd = bid & 7, loc = bid >> 3;        // loc 0..63
    const int jb2 = (xcd & 3) * 4 + (loc & 3);      // 0..15 weight group
    const int blockB = ((xcd >> 2) * 16 + (loc >> 2)) * BM;  // batch base

    const bf16* Asrc = hread + (size_t)blockB * HH;
    const bf16* Bsrc = Wr + (size_t)jb2 * 256 * HH;

    const int r8  = lane >> 3;        // 0..7
    const int gc  = (lane & 7) ^ r8;  // swizzled global 16B-chunk for staging
    const int swr = l15 & 7;          // read-side swizzle key (row & 7)

    // epilogue constants; bias folded into acc init
    float bsvv[2][4], wov[2];
#pragma unroll
    for (int jh = 0; jh < 2; jh++) {
        const int j = jb2 * 64 + waveN * 32 + jh * 16 + l15;
#pragma unroll
        for (int g = 0; g < 4; g++) bsvv[jh][g] = biasp[g * HH + j];
        wov[jh] = Wout[j];
    }

    f32x4 acc[4][8]; // [m-tile][gate*2 + j-half], bias-initialized
#pragma unroll
    for (int mi = 0; mi < 4; mi++)
#pragma unroll
        for (int g = 0; g < 4; g++)
#pragma unroll
            for (int jh = 0; jh < 2; jh++) {
                const float bv = bsvv[jh][g];
                acc[mi][g * 2 + jh] = (f32x4){bv, bv, bv, bv};
            }

    for (int k0 = 0; k0 < HH; k0 += BKK) {
        // A: wave stages rows [w*32, w*32+32) — 4 calls (8 rows x 128 B each)
#pragma unroll
        for (int c2 = 0; c2 < 4; c2++) {
            const int rowb = w * 32 + c2 * 8;
            gload_lds16(Asrc + (size_t)(rowb + r8) * HH + k0 + gc * 8, &As[rowb][0]);
        }
        // B: wave stages rows [w*64, w*64+64) — 8 calls
#pragma unroll
        for (int c2 = 0; c2 < 8; c2++) {
            const int rowb = w * 64 + c2 * 8;
            gload_lds16(Bsrc + (size_t)(rowb + r8) * HH + k0 + gc * 8, &Bs[rowb][0]);
        }
        asm volatile("s_waitcnt vmcnt(0)" ::: "memory");
        __syncthreads();
#pragma unroll
        for (int kk = 0; kk < 2; kk++) {
            v8bf a[4], b[8];
            const int pch = ((kk * 4 + quad) ^ swr) * 8;
#pragma unroll
            for (int mi = 0; mi < 4; mi++)
                a[mi] = *(const v8bf*)&As[waveM * 64 + mi * 16 + l15][pch];
#pragma unroll
            for (int g = 0; g < 4; g++)
#pragma unroll
                for (int jh = 0; jh < 2; jh++)
                    b[g * 2 + jh] =
                        *(const v8bf*)&Bs[g * 64 + waveN * 32 + jh * 16 + l15][pch];
#pragma unroll
            for (int mi = 0; mi < 4; mi++)
#pragma unroll
                for (int nt = 0; nt < 8; nt++)
                    acc[mi][nt] = __builtin_amdgcn_mfma_f32_16x16x32_bf16(
                        a[mi], b[nt], acc[mi][nt], 0, 0, 0);
        }
        __syncthreads();
    }

    // Epilogue: acc[mi][g*2+jh][r] = gate g (bias incl.) at (batch, j):
    //   batch = blockB + waveM*64 + mi*16 + quad*4 + r
    //   j     = jb2*64 + waveN*32 + jh*16 + l15
#pragma unroll
    for (int mi = 0; mi < 4; mi++) {
#pragma unroll
        for (int r = 0; r < 4; r++) {
            const int b = blockB + waveM * 64 + mi * 16 + quad * 4 + r;
            float pacc = 0.0f;
#pragma unroll
            for (int jh = 0; jh < 2; jh++) {
                const int j = jb2 * 64 + waveN * 32 + jh * 16 + l15;
                const float gi = acc[mi][0 + jh][r];
                const float gf = acc[mi][2 + jh][r];
                const float gg = acc[mi][4 + jh][r];
                const float go = acc[mi][6 + jh][r];
                const float cprev = (float)cbuf[(size_t)b * HH + j];
                const float cn = fast_sigmoid(gf) * cprev
                               + fast_sigmoid(gi) * fast_tanh(gg);
                cbuf[(size_t)b * HH + j] = (bf16)cn;   // in-place, 1 owner/elem
                const float hn = fast_sigmoid(go) * fast_tanh(cn);
                hwrite[(size_t)b * HH + j] = (bf16)hn;
                pacc += hn * wov[jh];
            }
            pacc += __shfl_xor(pacc, 1);
            pacc += __shfl_xor(pacc, 2);
            pacc += __shfl_xor(pacc, 4);
            pacc += __shfl_xor(pacc, 8);
            if (l15 == 0) atomicAdd(&predbuf_w[b], pacc);
        }
    }
}

// ---- Output transpose: out[b][t] = pred_t[b] ------------------------------

__global__ void write_out(const float* __restrict__ predbuf, float* __restrict__ out) {
    int idx = blockIdx.x * blockDim.x + threadIdx.x;
    if (idx < BB * TT) {
        int t = idx & (TT - 1);
        int b = idx >> 7;
        out[idx] = predbuf[(size_t)(t + 1) * BB + b];
    }
}

// ---- Host launch -----------------------------------------------------------

extern "C" void kernel_launch(void* const* d_in, const int* in_sizes, int n_in,
                              void* d_out, int out_size, void* d_ws, size_t ws_size,
                              hipStream_t stream) {
    const float* hidden = (const float*)d_in[0];
    const float* cell   = (const float*)d_in[1];
    const float* Wih    = (const float*)d_in[2];
    const float* Whh    = (const float*)d_in[3];
    const float* bih    = (const float*)d_in[4];
    const float* bhh    = (const float*)d_in[5];
    const float* Wout   = (const float*)d_in[6];
    const float* bout   = (const float*)d_in[7];
    float* out = (float*)d_out;

    char* ws = (char*)d_ws;
    bf16* Wr0 = (bf16*)ws;       ws += (size_t)4 * HH * HH * 2;   // 8 MB
    bf16* Wr1 = (bf16*)ws;       ws += (size_t)4 * HH * HH * 2;   // 8 MB
    bf16* hb0 = (bf16*)ws;       ws += (size_t)BB * HH * 2;       // 8 MB
    bf16* hb1 = (bf16*)ws;       ws += (size_t)BB * HH * 2;       // 8 MB
    bf16* cbuf = (bf16*)ws;      ws += (size_t)BB * HH * 2;       // 8 MB
    float* bias0 = (float*)ws;   ws += (size_t)4 * HH * 4;        // 16 KB
    float* bias1 = (float*)ws;   ws += (size_t)4 * HH * 4;        // 16 KB
    float* predbuf = (float*)ws; ws += (size_t)(TT + 1) * BB * 4; // 2.1 MB

    prep_weights<<<(4 * HH * HH + 255) / 256, 256, 0, stream>>>(
        Whh, bih, bhh, Wih, Wout, bout, Wr0, Wr1, bias0, bias1);
    prep_h<<<(BB * HH + 255) / 256, 256, 0, stream>>>(hidden, hb0);
    prep_c<<<(BB * HH + 255) / 256, 256, 0, stream>>>(cell, cbuf);
    prep_pred<<<((TT + 1) * BB + 255) / 256, 256, 0, stream>>>(predbuf, bout);

    bf16* hb[2] = {hb0, hb1};
    for (int t = 0; t < TT; t++) {
        const bf16* hr = hb[t & 1];
        bf16* hw = hb[(t + 1) & 1];
        const bf16* Wr   = (t == 0) ? Wr0 : Wr1;
        const float* bsp = (t == 0) ? bias0 : bias1;
        lstm_step<<<512, 256, 0, stream>>>(
            hr, hw, cbuf, Wr, bsp, Wout, predbuf + (size_t)(t + 1) * BB);
    }

    write_out<<<(BB * TT + 255) / 256, 256, 0, stream>>>(predbuf, out);
}